// Round 11
// baseline (168.299 us; speedup 1.0000x reference)
//
#include <hip/hip_runtime.h>

#define B_ 8
#define C_ 512
#define D_ 128
#define LDG 132   // gram LDS row stride (u16): 2-way-free gather
#define LDO 136   // k_out LDS row stride (u16): b128-aligned rows
#define LDK 136   // fallback ks row stride
#define LDT 40    // fallback kt row stride

typedef __bf16 v8bf __attribute__((ext_vector_type(8)));
typedef float v4f __attribute__((ext_vector_type(4)));
typedef float fvec4 __attribute__((ext_vector_type(4)));
typedef unsigned short u16;
typedef u16 u16x4 __attribute__((ext_vector_type(4)));

// f32 -> bf16 round-to-nearest-even
__device__ __forceinline__ u16 f2bf(float f) {
  unsigned u = __builtin_bit_cast(unsigned, f);
  u = u + 0x7FFFu + ((u >> 16) & 1u);
  return (u16)(u >> 16);
}

// ---- 256-thread helpers (k_out / fallback) ----
__device__ __forceinline__ void load_chunk(const float* __restrict__ Kbase,
                                           int tid, fvec4* pf) {
#pragma unroll
  for (int i = 0; i < 4; ++i)
    pf[i] = *(const fvec4*)(Kbase + i * 1024 + tid * 4);
}
template <int STRIDE>
__device__ __forceinline__ void lds_put(const fvec4* pf, u16* ksb, int tid) {
  const int d0 = (tid & 31) * 4;
  const int rb = tid >> 5;
#pragma unroll
  for (int i = 0; i < 4; ++i) {
    const int r = i * 8 + rb;
    fvec4 v = pf[i];
    u16x4 u = {f2bf(v[0]), f2bf(v[1]), f2bf(v[2]), f2bf(v[3])};
    *(u16x4*)&ksb[r * STRIDE + d0] = u;
  }
}

// ---- 512-thread helpers (k_gp2) ----
__device__ __forceinline__ void load_chunk2(const float* __restrict__ Kbase,
                                            int tid, fvec4* pf) {
#pragma unroll
  for (int i = 0; i < 2; ++i)
    pf[i] = *(const fvec4*)(Kbase + i * 2048 + tid * 4);
}
__device__ __forceinline__ void lds_put2(const fvec4* pf, u16* ksb, int tid) {
  const int d0 = (tid & 31) * 4;
  const int rb = tid >> 5;  // 0..15
#pragma unroll
  for (int i = 0; i < 2; ++i) {
    fvec4 v = pf[i];
    u16x4 u = {f2bf(v[0]), f2bf(v[1]), f2bf(v[2]), f2bf(v[3])};
    *(u16x4*)&ksb[(i * 16 + rb) * LDG + d0] = u;
  }
}

// ====== K1: per-batch Gram + REGISTER prefix (no cross-block comms) ========
// grid 8 blocks x 512 thr (8 waves). Block b loops its 16 chunks with
// double-buffered LDS; running state M stays in f32 registers.
// Per chunk: write M'[b][t]=bf16(carry+run) (exclusive), then run += G_t.
__global__ __launch_bounds__(512, 1) void k_gp2(const float* __restrict__ K,
                                                const float* __restrict__ carry,
                                                u16* __restrict__ Mp,
                                                float* __restrict__ tot) {
  const int b = blockIdx.x;
  const int tid = threadIdx.x;
  const int w = tid >> 6;           // 0..7: wave owns row-band 16w..16w+15
  const int l = tid & 63, lr = l & 15, lg = l >> 4;

  __shared__ u16 ks[2][32 * LDG];

  const float* Kb = K + (size_t)(b * C_) * D_;

  // stage chunk 0
  fvec4 pf[2];
  load_chunk2(Kb, tid, pf);

  // carry fragments at the positions this lane writes: (16w+4lg+j, 16n+lr)
  float cv[8][4];
#pragma unroll
  for (int n = 0; n < 8; ++n)
#pragma unroll
    for (int j = 0; j < 4; ++j)
      cv[n][j] = carry[(size_t)(16 * w + 4 * lg + j) * 128 + 16 * n + lr];

  v4f run[8];
#pragma unroll
  for (int n = 0; n < 8; ++n) run[n] = (v4f){0.f, 0.f, 0.f, 0.f};

  lds_put2(pf, ks[0], tid);
  __syncthreads();

  int cur = 0;
  for (int cc = 0; cc < 16; ++cc) {
    const bool more = (cc < 15);
    fvec4 nf[2];
    if (more) load_chunk2(Kb + (size_t)(cc + 1) * 32 * D_, tid, nf);

    // gather 8 B-frags: fb[x][e] = bf16K[8lg+e][16x+lr]; A-frag = fb[w]
    v8bf fb[8];
#pragma unroll
    for (int x = 0; x < 8; ++x) {
      u16 tmp[8];
#pragma unroll
      for (int e = 0; e < 8; ++e)
        tmp[e] = ks[cur][(8 * lg + e) * LDG + 16 * x + lr];
      fb[x] = *(const v8bf*)tmp;
    }

    // write exclusive-prefix M' for this chunk (independent of this G_t)
    {
      u16* mrow = Mp + (size_t)(b * 16 + cc) * 16384;
#pragma unroll
      for (int n = 0; n < 8; ++n)
#pragma unroll
        for (int j = 0; j < 4; ++j)
          mrow[(size_t)(16 * w + 4 * lg + j) * 128 + 16 * n + lr] =
              f2bf(cv[n][j] + run[n][j]);
    }

    // G_t tiles for row-band w, all 8 col-tiles; accumulate into run
#pragma unroll
    for (int n = 0; n < 8; ++n) {
      v4f z = {0.f, 0.f, 0.f, 0.f};
      v4f a = __builtin_amdgcn_mfma_f32_16x16x32_bf16(fb[w], fb[n], z, 0, 0, 0);
      run[n] += a;
    }

    if (more) {
      lds_put2(nf, ks[cur ^ 1], tid);
      cur ^= 1;
    }
    __syncthreads();
  }

  // tot[b] = inclusive sum over all 16 chunks (f32)
#pragma unroll
  for (int n = 0; n < 8; ++n)
#pragma unroll
    for (int j = 0; j < 4; ++j)
      tot[(size_t)b * 16384 + (size_t)(16 * w + 4 * lg + j) * 128 + 16 * n +
          lr] = run[n][j];
}

// ===== K2: out = Q*M'^T + intra-chunk causal S*K ; t==16 blocks do out2 ====
// (byte-identical to the proven round-6 k_out)
__global__ __launch_bounds__(256, 1) void k_out(
    const float* __restrict__ Q, const float* __restrict__ K,
    const u16* __restrict__ Mp, const float* __restrict__ tot,
    const float* __restrict__ carry, float* __restrict__ out,
    float* __restrict__ out2) {
  const int t = blockIdx.x, b = blockIdx.y;
  const int tid = threadIdx.x;

  if (t == 16) {  // out2 = carry + mean_b(tot)
    const int e0 = b * 2048 + tid * 8;
    fvec4 s0 = {0.f, 0.f, 0.f, 0.f}, s1 = {0.f, 0.f, 0.f, 0.f};
#pragma unroll
    for (int bb = 0; bb < 8; ++bb) {
      s0 += *(const fvec4*)(tot + (size_t)bb * 16384 + e0);
      s1 += *(const fvec4*)(tot + (size_t)bb * 16384 + e0 + 4);
    }
    fvec4 c0 = *(const fvec4*)(carry + e0);
    fvec4 c1 = *(const fvec4*)(carry + e0 + 4);
    *(fvec4*)(out2 + e0) = c0 + 0.125f * s0;
    *(fvec4*)(out2 + e0 + 4) = c1 + 0.125f * s1;
    return;
  }

  const int w = tid >> 6, l = tid & 63, lr = l & 15, lg = l >> 4;
  const int wr = (w & 1) * 16, wc = (w >> 1) * 64, sc0 = (w >> 1) * 16;
  const int r0 = t * 32;

  __shared__ u16 ks[32 * LDO];
  __shared__ u16 sl[32 * 40];

  fvec4 pf[4];
  load_chunk(K + (size_t)(b * C_ + r0) * D_, tid, pf);

  v8bf qf[4];
  {
    const float* qrow = Q + (size_t)(b * C_ + r0 + wr + lr) * D_;
#pragma unroll
    for (int kk = 0; kk < 4; ++kk) {
      const float* p = qrow + kk * 32 + 8 * lg;
      fvec4 a = *(const fvec4*)p;
      fvec4 c2 = *(const fvec4*)(p + 4);
      u16 tmp[8] = {f2bf(a[0]),  f2bf(a[1]),  f2bf(a[2]),  f2bf(a[3]),
                    f2bf(c2[0]), f2bf(c2[1]), f2bf(c2[2]), f2bf(c2[3])};
      qf[kk] = *(const v8bf*)tmp;
    }
  }

  v8bf mf[16];
  {
    const u16* mp = Mp + (size_t)(b * 16 + t) * 16384;
#pragma unroll
    for (int kk = 0; kk < 4; ++kk)
#pragma unroll
      for (int n = 0; n < 4; ++n)
        mf[kk * 4 + n] = *(const v8bf*)(mp + (size_t)(wc + 16 * n + lr) * 128 +
                                        32 * kk + 8 * lg);
  }

  lds_put<LDO>(pf, ks, tid);
  __syncthreads();

  v8bf sb[4];
#pragma unroll
  for (int kk = 0; kk < 4; ++kk)
    sb[kk] = *(const v8bf*)&ks[(sc0 + lr) * LDO + 32 * kk + 8 * lg];

  v8bf pb[4];
#pragma unroll
  for (int n = 0; n < 4; ++n) {
    u16 tmp[8];
#pragma unroll
    for (int e = 0; e < 8; ++e)
      tmp[e] = ks[(8 * lg + e) * LDO + wc + 16 * n + lr];
    pb[n] = *(const v8bf*)tmp;
  }

  v4f sacc = {0.f, 0.f, 0.f, 0.f};
#pragma unroll
  for (int kk = 0; kk < 4; ++kk)
    sacc =
        __builtin_amdgcn_mfma_f32_16x16x32_bf16(qf[kk], sb[kk], sacc, 0, 0, 0);
#pragma unroll
  for (int j = 0; j < 4; ++j) {
    const int sr = wr + lg * 4 + j;
    const int sc = sc0 + lr;
    float v = sacc[j];
    if (sc > sr) v = 0.f;
    sl[sr * 40 + sc] = f2bf(v);
  }

  v4f acc[4] = {{0.f, 0.f, 0.f, 0.f}, {0.f, 0.f, 0.f, 0.f},
                {0.f, 0.f, 0.f, 0.f}, {0.f, 0.f, 0.f, 0.f}};
#pragma unroll
  for (int kk = 0; kk < 4; ++kk)
#pragma unroll
    for (int n = 0; n < 4; ++n)
      acc[n] = __builtin_amdgcn_mfma_f32_16x16x32_bf16(qf[kk], mf[kk * 4 + n],
                                                       acc[n], 0, 0, 0);
  __syncthreads();

  v8bf af = *(const v8bf*)&sl[(wr + lr) * 40 + lg * 8];
#pragma unroll
  for (int n = 0; n < 4; ++n)
    acc[n] =
        __builtin_amdgcn_mfma_f32_16x16x32_bf16(af, pb[n], acc[n], 0, 0, 0);

#pragma unroll
  for (int n = 0; n < 4; ++n)
#pragma unroll
    for (int j = 0; j < 4; ++j)
      out[(size_t)(b * C_ + r0 + wr + lg * 4 + j) * D_ + wc + n * 16 + lr] =
          acc[n][j];
}

// ================= zero-ws fallback (never expected) =======================
__device__ __forceinline__ int kt_idx(int d, int r) {
  return d * LDT + ((((r >> 3) ^ ((d >> 2) & 3))) << 3) + (r & 7);
}
__device__ __forceinline__ v8bf kt_frag(const u16* ktb, int col, int lg) {
  return *(const v8bf*)&ktb[col * LDT + (((lg ^ ((col >> 2) & 3))) << 3)];
}
__device__ __forceinline__ void write_stage(const fvec4* pf, u16* ksb, u16* ktb,
                                            int tid) {
  const int d0 = (tid & 31) * 4;
  const int rb = tid >> 5;
#pragma unroll
  for (int i = 0; i < 4; ++i) {
    const int r = i * 8 + rb;
    fvec4 v = pf[i];
    u16 h0 = f2bf(v[0]), h1 = f2bf(v[1]), h2 = f2bf(v[2]), h3 = f2bf(v[3]);
    u16x4 u = {h0, h1, h2, h3};
    *(u16x4*)&ksb[r * LDK + d0] = u;
    ktb[kt_idx(d0 + 0, r)] = h0;
    ktb[kt_idx(d0 + 1, r)] = h1;
    ktb[kt_idx(d0 + 2, r)] = h2;
    ktb[kt_idx(d0 + 3, r)] = h3;
  }
}

__global__ __launch_bounds__(256) void k_proj_fb(
    const float* __restrict__ Q, const float* __restrict__ K,
    const float* __restrict__ carry, float* __restrict__ out) {
  const int t = blockIdx.x, b = blockIdx.y;
  const int tid = threadIdx.x;
  const int w = tid >> 6, l = tid & 63, lr = l & 15, lg = l >> 4;
  const int wr = (w & 1) * 16, wc = (w >> 1) * 64;
  const int r0 = t * 32;

  __shared__ u16 ks[2][32 * LDK];
  __shared__ u16 kt[2][128 * LDT];
  __shared__ u16 sl[32 * 40];

  const float* Kb0 = K + (size_t)(b * C_) * D_;
  fvec4 pf[4];
  load_chunk(Kb0, tid, pf);

  v8bf qf[4];
  {
    const float* qrow = Q + (size_t)(b * C_ + r0 + wr + lr) * D_;
#pragma unroll
    for (int kk = 0; kk < 4; ++kk) {
      const float* p = qrow + kk * 32 + lg * 8;
      fvec4 a = *(const fvec4*)p;
      fvec4 c2 = *(const fvec4*)(p + 4);
      u16 tmp[8] = {f2bf(a[0]),  f2bf(a[1]),  f2bf(a[2]),  f2bf(a[3]),
                    f2bf(c2[0]), f2bf(c2[1]), f2bf(c2[2]), f2bf(c2[3])};
      qf[kk] = *(const v8bf*)tmp;
    }
  }

  v4f acc[4] = {{0.f, 0.f, 0.f, 0.f}, {0.f, 0.f, 0.f, 0.f},
                {0.f, 0.f, 0.f, 0.f}, {0.f, 0.f, 0.f, 0.f}};
#pragma unroll
  for (int kk = 0; kk < 4; ++kk) {
#pragma unroll
    for (int n = 0; n < 4; ++n) {
      const float* p =
          carry + (size_t)(wc + n * 16 + lr) * D_ + kk * 32 + lg * 8;
      fvec4 a = *(const fvec4*)p;
      fvec4 c2 = *(const fvec4*)(p + 4);
      u16 tmp[8] = {f2bf(a[0]),  f2bf(a[1]),  f2bf(a[2]),  f2bf(a[3]),
                    f2bf(c2[0]), f2bf(c2[1]), f2bf(c2[2]), f2bf(c2[3])};
      acc[n] = __builtin_amdgcn_mfma_f32_16x16x32_bf16(
          qf[kk], *(const v8bf*)tmp, acc[n], 0, 0, 0);
    }
  }

  write_stage(pf, ks[0], kt[0], tid);
  __syncthreads();

  int cur = 0;
  const int sc0 = (w >> 1) * 16;
  for (int cc = 0; cc <= t; ++cc) {
    const bool more = (cc < t);
    fvec4 nf[4];
    if (more) load_chunk(Kb0 + (size_t)(cc + 1) * 32 * D_, tid, nf);

    v4f sacc = {0.f, 0.f, 0.f, 0.f};
#pragma unroll
    for (int kk = 0; kk < 4; ++kk) {
      v8bf bf = *(const v8bf*)&ks[cur][(sc0 + lr) * LDK + kk * 32 + lg * 8];
      sacc = __builtin_amdgcn_mfma_f32_16x16x32_bf16(qf[kk], bf, sacc, 0, 0, 0);
    }
    const bool diag = (cc == t);
#pragma unroll
    for (int j = 0; j < 4; ++j) {
      const int sr = wr + lg * 4 + j;
      const int sc = sc0 + lr;
      float v = sacc[j];
      if (diag && sc > sr) v = 0.f;
      sl[sr * 40 + sc] = f2bf(v);
    }
    __syncthreads();

    v8bf af = *(const v8bf*)&sl[(wr + lr) * 40 + lg * 8];
#pragma unroll
    for (int n = 0; n < 4; ++n) {
      v8bf bf = kt_frag(kt[cur], wc + n * 16 + lr, lg);
      acc[n] = __builtin_amdgcn_mfma_f32_16x16x32_bf16(af, bf, acc[n], 0, 0, 0);
    }
    if (more) {
      write_stage(nf, ks[cur ^ 1], kt[cur ^ 1], tid);
      cur ^= 1;
    }
    __syncthreads();
  }

#pragma unroll
  for (int n = 0; n < 4; ++n)
#pragma unroll
    for (int j = 0; j < 4; ++j)
      out[(size_t)(b * C_ + r0 + wr + lg * 4 + j) * D_ + wc + n * 16 + lr] =
          acc[n][j];
}

__global__ __launch_bounds__(256) void k_syrk_direct(
    const float* __restrict__ K, const float* __restrict__ carry,
    float* __restrict__ out2) {
  const int tid = threadIdx.x;
  const int w = tid >> 6, l = tid & 63, lr = l & 15, lg = l >> 4;
  __shared__ u16 kt[2][128 * LDT];

  v4f acc[2][8];
#pragma unroll
  for (int mi = 0; mi < 2; ++mi)
#pragma unroll
    for (int n = 0; n < 8; ++n) acc[mi][n] = (v4f){0.f, 0.f, 0.f, 0.f};

  fvec4 pf[4];
  load_chunk(K, tid, pf);
  {
    const int d0 = (tid & 31) * 4;
    const int rb = tid >> 5;
#pragma unroll
    for (int i = 0; i < 4; ++i) {
      const int r = i * 8 + rb;
      fvec4 v = pf[i];
      kt[0][kt_idx(d0 + 0, r)] = f2bf(v[0]);
      kt[0][kt_idx(d0 + 1, r)] = f2bf(v[1]);
      kt[0][kt_idx(d0 + 2, r)] = f2bf(v[2]);
      kt[0][kt_idx(d0 + 3, r)] = f2bf(v[3]);
    }
  }
  __syncthreads();
  int cur = 0;
  for (int g = 0; g < 128; ++g) {
    const bool more = (g < 127);
    fvec4 nf[4];
    if (more) load_chunk(K + (size_t)(g + 1) * 32 * D_, tid, nf);
    v8bf fr[8];
#pragma unroll
    for (int x = 0; x < 8; ++x) fr[x] = kt_frag(kt[cur], x * 16 + lr, lg);
#pragma unroll
    for (int mi = 0; mi < 2; ++mi)
#pragma unroll
      for (int n = 0; n < 8; ++n)
        acc[mi][n] = __builtin_amdgcn_mfma_f32_16x16x32_bf16(
            fr[2 * w + mi], fr[n], acc[mi][n], 0, 0, 0);
    if (more) {
      const int d0 = (tid & 31) * 4;
      const int rb = tid >> 5;
      u16* kb = kt[cur ^ 1];
#pragma unroll
      for (int i = 0; i < 4; ++i) {
        const int r = i * 8 + rb;
        fvec4 v = nf[i];
        kb[kt_idx(d0 + 0, r)] = f2bf(v[0]);
        kb[kt_idx(d0 + 1, r)] = f2bf(v[1]);
        kb[kt_idx(d0 + 2, r)] = f2bf(v[2]);
        kb[kt_idx(d0 + 3, r)] = f2bf(v[3]);
      }
      cur ^= 1;
    }
    __syncthreads();
  }
#pragma unroll
  for (int mi = 0; mi < 2; ++mi)
#pragma unroll
    for (int n = 0; n < 8; ++n)
#pragma unroll
      for (int j = 0; j < 4; ++j) {
        const int idx = (16 * (2 * w + mi) + 4 * lg + j) * 128 + 16 * n + lr;
        out2[idx] = carry[idx] + 0.125f * acc[mi][n][j];
      }
}

extern "C" void kernel_launch(void* const* d_in, const int* in_sizes, int n_in,
                              void* d_out, int out_size, void* d_ws,
                              size_t ws_size, hipStream_t stream) {
  const float* Q = (const float*)d_in[0];
  const float* K = (const float*)d_in[1];
  const float* carry = (const float*)d_in[2];
  float* out = (float*)d_out;
  float* out2 = out + (size_t)B_ * C_ * D_;

  // ws: M' bf16 [128][16384] (4 MiB) | tot f32 [8][16384] (512 KiB)
  const size_t nMu = (size_t)128 * 16384;  // u16 elems
  const size_t need = nMu * sizeof(u16) + (size_t)8 * 16384 * sizeof(float);

  if (ws_size >= need) {
    u16* Mp = (u16*)d_ws;
    float* tot = (float*)(Mp + nMu);
    k_gp2<<<8, 512, 0, stream>>>(K, carry, Mp, tot);
    k_out<<<dim3(17, 8), 256, 0, stream>>>(Q, K, Mp, tot, carry, out, out2);
  } else {
    k_proj_fb<<<dim3(16, 8), 256, 0, stream>>>(Q, K, carry, out);
    k_syrk_direct<<<1, 256, 0, stream>>>(K, carry, out2);
  }
}

// Round 12
// 30.232 us; speedup vs baseline: 5.5669x; 5.5669x over previous
//
#include <hip/hip_runtime.h>

#define B_ 8
#define C_ 512
#define D_ 128
#define LDG 132   // gram LDS row stride (u16): 2-way-free gather
#define LDO 136   // k_out LDS row stride (u16): b128-aligned rows
#define LDK 136   // fallback ks row stride
#define LDT 40    // fallback kt row stride

typedef __bf16 v8bf __attribute__((ext_vector_type(8)));
typedef float v4f __attribute__((ext_vector_type(4)));
typedef float fvec4 __attribute__((ext_vector_type(4)));
typedef unsigned short u16;
typedef u16 u16x4 __attribute__((ext_vector_type(4)));
typedef u16 u16x8 __attribute__((ext_vector_type(8)));

// f32 -> bf16 round-to-nearest-even
__device__ __forceinline__ u16 f2bf(float f) {
  unsigned u = __builtin_bit_cast(unsigned, f);
  u = u + 0x7FFFu + ((u >> 16) & 1u);
  return (u16)(u >> 16);
}
__device__ __forceinline__ float bf2f(u16 h) {
  unsigned u = ((unsigned)h) << 16;
  return __builtin_bit_cast(float, u);
}

// Coalesced 32x128 f32 chunk load: 4 fvec4/thread, 4B lane stride.
__device__ __forceinline__ void load_chunk(const float* __restrict__ Kbase,
                                           int tid, fvec4* pf) {
#pragma unroll
  for (int i = 0; i < 4; ++i)
    pf[i] = *(const fvec4*)(Kbase + i * 1024 + tid * 4);
}

// Write staged chunk to LDS row-major [32][stride] bf16 (b64 stores).
template <int STRIDE>
__device__ __forceinline__ void lds_put(const fvec4* pf, u16* ksb, int tid) {
  const int d0 = (tid & 31) * 4;
  const int rb = tid >> 5;
#pragma unroll
  for (int i = 0; i < 4; ++i) {
    const int r = i * 8 + rb;
    fvec4 v = pf[i];
    u16x4 u = {f2bf(v[0]), f2bf(v[1]), f2bf(v[2]), f2bf(v[3])};
    *(u16x4*)&ksb[r * STRIDE + d0] = u;
  }
}

// ========== K1: per-chunk Gram G[b][t] = K_t^T K_t, bf16 row-major =========
// (byte-identical to the proven round-6 k_gram)
__global__ __launch_bounds__(256, 1) void k_gram(const float* __restrict__ K,
                                                 u16* __restrict__ G) {
  const int t = blockIdx.x, b = blockIdx.y;
  const int tid = threadIdx.x;
  const int w = tid >> 6, l = tid & 63, lr = l & 15, lg = l >> 4;

  __shared__ u16 ks[32 * LDG];

  fvec4 pf[4];
  load_chunk(K + (size_t)(b * C_ + t * 32) * D_, tid, pf);
  lds_put<LDG>(pf, ks, tid);
  __syncthreads();

  v8bf fr[8];
#pragma unroll
  for (int n = 0; n < 8; ++n) {
    u16 tmp[8];
#pragma unroll
    for (int e = 0; e < 8; ++e) tmp[e] = ks[(8 * lg + e) * LDG + 16 * n + lr];
    fr[n] = *(const v8bf*)tmp;
  }
  u16* Gp = G + (size_t)(b * 16 + t) * 16384;
#pragma unroll
  for (int mi = 0; mi < 2; ++mi) {
    v8bf am = fr[2 * w + mi];
#pragma unroll
    for (int n = 0; n < 8; ++n) {
      v4f z = {0.f, 0.f, 0.f, 0.f};
      v4f a = __builtin_amdgcn_mfma_f32_16x16x32_bf16(am, fr[n], z, 0, 0, 0);
#pragma unroll
      for (int j = 0; j < 4; ++j)
        Gp[(size_t)(32 * w + 16 * mi + 4 * lg + j) * 128 + 16 * n + lr] =
            f2bf(a[j]);
    }
  }
}

// ===== K2: streaming prefix (in-block) + out = Q*M'^T + causal diag S*K ====
// grid (17,8), 256 thr / 4 waves. Block (t,b):
//   run[64] = carry + sum_{t'<t} G[b][t']   (8 batched b128 loads / iter,
//   no barrier, no LDS, no MFMA in the loop) -> LDS ml -> MFMA frags.
// t==16 blocks: out2 = carry + mean_b(sum_t G)  (streaming, 8 loads in flight)
__global__ __launch_bounds__(256, 1) void k_out2(
    const float* __restrict__ Q, const float* __restrict__ K,
    const u16* __restrict__ G, const float* __restrict__ carry,
    float* __restrict__ out, float* __restrict__ out2) {
  const int t = blockIdx.x, b = blockIdx.y;
  const int tid = threadIdx.x;

  if (t == 16) {  // out2 = carry + (1/8) sum over all 128 chunk-Grams
    const int e0 = b * 2048 + tid * 8;
    float s0[8] = {0.f, 0.f, 0.f, 0.f, 0.f, 0.f, 0.f, 0.f};
    float s1[8] = {0.f, 0.f, 0.f, 0.f, 0.f, 0.f, 0.f, 0.f};
#pragma unroll 4
    for (int p = 0; p < 128; p += 2) {
      u16x8 ga = *(const u16x8*)(G + (size_t)p * 16384 + e0);
      u16x8 gb = *(const u16x8*)(G + (size_t)(p + 1) * 16384 + e0);
#pragma unroll
      for (int i = 0; i < 8; ++i) {
        s0[i] += bf2f(ga[i]);
        s1[i] += bf2f(gb[i]);
      }
    }
#pragma unroll
    for (int i = 0; i < 8; ++i)
      out2[e0 + i] = carry[e0 + i] + 0.125f * (s0[i] + s1[i]);
    return;
  }

  const int w = tid >> 6, l = tid & 63, lr = l & 15, lg = l >> 4;
  const int wr = (w & 1) * 16, wc = (w >> 1) * 64, sc0 = (w >> 1) * 16;
  const int r0 = t * 32;

  __shared__ u16 ml[128 * LDO];  // M' tile (bf16), full 128x128
  __shared__ u16 ks[32 * LDO];   // K chunk
  __shared__ u16 sl[32 * 40];    // masked S chunk

  // issue K-chunk + Q loads first; HBM latency hides under the prefix loop
  fvec4 pf[4];
  load_chunk(K + (size_t)(b * C_ + r0) * D_, tid, pf);

  v8bf qf[4];
  {
    const float* qrow = Q + (size_t)(b * C_ + r0 + wr + lr) * D_;
#pragma unroll
    for (int kk = 0; kk < 4; ++kk) {
      const float* p = qrow + kk * 32 + 8 * lg;
      fvec4 a = *(const fvec4*)p;
      fvec4 c2 = *(const fvec4*)(p + 4);
      u16 tmp[8] = {f2bf(a[0]),  f2bf(a[1]),  f2bf(a[2]),  f2bf(a[3]),
                    f2bf(c2[0]), f2bf(c2[1]), f2bf(c2[2]), f2bf(c2[3])};
      qf[kk] = *(const v8bf*)tmp;
    }
  }

  // ---- streaming prefix: run = carry + sum_{t'<t} G[b][t'] (64 elems/thr) --
  float run[64];
#pragma unroll
  for (int g = 0; g < 8; ++g) {
    fvec4 c0 = *(const fvec4*)(carry + g * 2048 + tid * 8);
    fvec4 c1 = *(const fvec4*)(carry + g * 2048 + tid * 8 + 4);
#pragma unroll
    for (int i = 0; i < 4; ++i) {
      run[g * 8 + i] = c0[i];
      run[g * 8 + 4 + i] = c1[i];
    }
  }
  {
    const u16* gb = G + (size_t)b * 16 * 16384;
    for (int tp = 0; tp < t; ++tp) {  // dynamic, uniform per block
      u16x8 gg[8];
#pragma unroll
      for (int g = 0; g < 8; ++g)
        gg[g] = *(const u16x8*)(gb + (size_t)tp * 16384 + g * 2048 + tid * 8);
#pragma unroll
      for (int g = 0; g < 8; ++g)
#pragma unroll
        for (int i = 0; i < 8; ++i) run[g * 8 + i] += bf2f(gg[g][i]);
    }
  }
  // scatter run -> ml (row-major [128][LDO]); elem e = g*2048 + tid*8 + i
  {
    const int mrow = tid >> 4;        // +16g
    const int mcol = (tid & 15) * 8;  // 8 contiguous cols
#pragma unroll
    for (int g = 0; g < 8; ++g) {
      u16x8 m;
#pragma unroll
      for (int i = 0; i < 8; ++i) m[i] = f2bf(run[g * 8 + i]);
      *(u16x8*)&ml[(g * 16 + mrow) * LDO + mcol] = m;
    }
  }

  lds_put<LDO>(pf, ks, tid);
  __syncthreads();

  // M' B-frags from LDS (b128)
  v8bf mf[16];
#pragma unroll
  for (int kk = 0; kk < 4; ++kk)
#pragma unroll
    for (int n = 0; n < 4; ++n)
      mf[kk * 4 + n] =
          *(const v8bf*)&ml[(wc + 16 * n + lr) * LDO + 32 * kk + 8 * lg];

  // S-step B-frags: row-major b128 LDS reads
  v8bf sb[4];
#pragma unroll
  for (int kk = 0; kk < 4; ++kk)
    sb[kk] = *(const v8bf*)&ks[(sc0 + lr) * LDO + 32 * kk + 8 * lg];

  // PV B-frags: transposed LDS gather
  v8bf pb[4];
#pragma unroll
  for (int n = 0; n < 4; ++n) {
    u16 tmp[8];
#pragma unroll
    for (int e = 0; e < 8; ++e)
      tmp[e] = ks[(8 * lg + e) * LDO + wc + 16 * n + lr];
    pb[n] = *(const v8bf*)tmp;
  }

  // S tile = Q * Kchunk^T (diagonal, causal mask), hand off via LDS
  v4f sacc = {0.f, 0.f, 0.f, 0.f};
#pragma unroll
  for (int kk = 0; kk < 4; ++kk)
    sacc =
        __builtin_amdgcn_mfma_f32_16x16x32_bf16(qf[kk], sb[kk], sacc, 0, 0, 0);
#pragma unroll
  for (int j = 0; j < 4; ++j) {
    const int sr = wr + lg * 4 + j;
    const int sc = sc0 + lr;
    float v = sacc[j];
    if (sc > sr) v = 0.f;
    sl[sr * 40 + sc] = f2bf(v);
  }

  // acc = Q * M'^T — overlaps the barrier wait
  v4f acc[4] = {{0.f, 0.f, 0.f, 0.f}, {0.f, 0.f, 0.f, 0.f},
                {0.f, 0.f, 0.f, 0.f}, {0.f, 0.f, 0.f, 0.f}};
#pragma unroll
  for (int kk = 0; kk < 4; ++kk)
#pragma unroll
    for (int n = 0; n < 4; ++n)
      acc[n] = __builtin_amdgcn_mfma_f32_16x16x32_bf16(qf[kk], mf[kk * 4 + n],
                                                       acc[n], 0, 0, 0);
  __syncthreads();

  // PV: acc += S * Kchunk
  v8bf af = *(const v8bf*)&sl[(wr + lr) * 40 + lg * 8];
#pragma unroll
  for (int n = 0; n < 4; ++n)
    acc[n] =
        __builtin_amdgcn_mfma_f32_16x16x32_bf16(af, pb[n], acc[n], 0, 0, 0);

  // epilogue: C/D layout col = lane&15, row = 4*(lane>>4)+j
#pragma unroll
  for (int n = 0; n < 4; ++n)
#pragma unroll
    for (int j = 0; j < 4; ++j)
      out[(size_t)(b * C_ + r0 + wr + lg * 4 + j) * D_ + wc + n * 16 + lr] =
          acc[n][j];
}

// ================= zero-ws fallback (never expected) =======================
__device__ __forceinline__ int kt_idx(int d, int r) {
  return d * LDT + ((((r >> 3) ^ ((d >> 2) & 3))) << 3) + (r & 7);
}
__device__ __forceinline__ v8bf kt_frag(const u16* ktb, int col, int lg) {
  return *(const v8bf*)&ktb[col * LDT + (((lg ^ ((col >> 2) & 3))) << 3)];
}
__device__ __forceinline__ void write_stage(const fvec4* pf, u16* ksb, u16* ktb,
                                            int tid) {
  const int d0 = (tid & 31) * 4;
  const int rb = tid >> 5;
#pragma unroll
  for (int i = 0; i < 4; ++i) {
    const int r = i * 8 + rb;
    fvec4 v = pf[i];
    u16 h0 = f2bf(v[0]), h1 = f2bf(v[1]), h2 = f2bf(v[2]), h3 = f2bf(v[3]);
    u16x4 u = {h0, h1, h2, h3};
    *(u16x4*)&ksb[r * LDK + d0] = u;
    ktb[kt_idx(d0 + 0, r)] = h0;
    ktb[kt_idx(d0 + 1, r)] = h1;
    ktb[kt_idx(d0 + 2, r)] = h2;
    ktb[kt_idx(d0 + 3, r)] = h3;
  }
}

__global__ __launch_bounds__(256) void k_proj_fb(
    const float* __restrict__ Q, const float* __restrict__ K,
    const float* __restrict__ carry, float* __restrict__ out) {
  const int t = blockIdx.x, b = blockIdx.y;
  const int tid = threadIdx.x;
  const int w = tid >> 6, l = tid & 63, lr = l & 15, lg = l >> 4;
  const int wr = (w & 1) * 16, wc = (w >> 1) * 64;
  const int r0 = t * 32;

  __shared__ u16 ks[2][32 * LDK];
  __shared__ u16 kt[2][128 * LDT];
  __shared__ u16 sl[32 * 40];

  const float* Kb0 = K + (size_t)(b * C_) * D_;
  fvec4 pf[4];
  load_chunk(Kb0, tid, pf);

  v8bf qf[4];
  {
    const float* qrow = Q + (size_t)(b * C_ + r0 + wr + lr) * D_;
#pragma unroll
    for (int kk = 0; kk < 4; ++kk) {
      const float* p = qrow + kk * 32 + lg * 8;
      fvec4 a = *(const fvec4*)p;
      fvec4 c2 = *(const fvec4*)(p + 4);
      u16 tmp[8] = {f2bf(a[0]),  f2bf(a[1]),  f2bf(a[2]),  f2bf(a[3]),
                    f2bf(c2[0]), f2bf(c2[1]), f2bf(c2[2]), f2bf(c2[3])};
      qf[kk] = *(const v8bf*)tmp;
    }
  }

  v4f acc[4] = {{0.f, 0.f, 0.f, 0.f}, {0.f, 0.f, 0.f, 0.f},
                {0.f, 0.f, 0.f, 0.f}, {0.f, 0.f, 0.f, 0.f}};
#pragma unroll
  for (int kk = 0; kk < 4; ++kk) {
#pragma unroll
    for (int n = 0; n < 4; ++n) {
      const float* p =
          carry + (size_t)(wc + n * 16 + lr) * D_ + kk * 32 + lg * 8;
      fvec4 a = *(const fvec4*)p;
      fvec4 c2 = *(const fvec4*)(p + 4);
      u16 tmp[8] = {f2bf(a[0]),  f2bf(a[1]),  f2bf(a[2]),  f2bf(a[3]),
                    f2bf(c2[0]), f2bf(c2[1]), f2bf(c2[2]), f2bf(c2[3])};
      acc[n] = __builtin_amdgcn_mfma_f32_16x16x32_bf16(
          qf[kk], *(const v8bf*)tmp, acc[n], 0, 0, 0);
    }
  }

  write_stage(pf, ks[0], kt[0], tid);
  __syncthreads();

  int cur = 0;
  const int sc0 = (w >> 1) * 16;
  for (int cc = 0; cc <= t; ++cc) {
    const bool more = (cc < t);
    fvec4 nf[4];
    if (more) load_chunk(Kb0 + (size_t)(cc + 1) * 32 * D_, tid, nf);

    v4f sacc = {0.f, 0.f, 0.f, 0.f};
#pragma unroll
    for (int kk = 0; kk < 4; ++kk) {
      v8bf bf = *(const v8bf*)&ks[cur][(sc0 + lr) * LDK + kk * 32 + lg * 8];
      sacc = __builtin_amdgcn_mfma_f32_16x16x32_bf16(qf[kk], bf, sacc, 0, 0, 0);
    }
    const bool diag = (cc == t);
#pragma unroll
    for (int j = 0; j < 4; ++j) {
      const int sr = wr + lg * 4 + j;
      const int sc = sc0 + lr;
      float v = sacc[j];
      if (diag && sc > sr) v = 0.f;
      sl[sr * 40 + sc] = f2bf(v);
    }
    __syncthreads();

    v8bf af = *(const v8bf*)&sl[(wr + lr) * 40 + lg * 8];
#pragma unroll
    for (int n = 0; n < 4; ++n) {
      v8bf bf = kt_frag(kt[cur], wc + n * 16 + lr, lg);
      acc[n] = __builtin_amdgcn_mfma_f32_16x16x32_bf16(af, bf, acc[n], 0, 0, 0);
    }
    if (more) {
      write_stage(nf, ks[cur ^ 1], kt[cur ^ 1], tid);
      cur ^= 1;
    }
    __syncthreads();
  }

#pragma unroll
  for (int n = 0; n < 4; ++n)
#pragma unroll
    for (int j = 0; j < 4; ++j)
      out[(size_t)(b * C_ + r0 + wr + lg * 4 + j) * D_ + wc + n * 16 + lr] =
          acc[n][j];
}

__global__ __launch_bounds__(256) void k_syrk_direct(
    const float* __restrict__ K, const float* __restrict__ carry,
    float* __restrict__ out2) {
  const int tid = threadIdx.x;
  const int w = tid >> 6, l = tid & 63, lr = l & 15, lg = l >> 4;
  __shared__ u16 kt[2][128 * LDT];

  v4f acc[2][8];
#pragma unroll
  for (int mi = 0; mi < 2; ++mi)
#pragma unroll
    for (int n = 0; n < 8; ++n) acc[mi][n] = (v4f){0.f, 0.f, 0.f, 0.f};

  fvec4 pf[4];
  load_chunk(K, tid, pf);
  {
    const int d0 = (tid & 31) * 4;
    const int rb = tid >> 5;
#pragma unroll
    for (int i = 0; i < 4; ++i) {
      const int r = i * 8 + rb;
      fvec4 v = pf[i];
      kt[0][kt_idx(d0 + 0, r)] = f2bf(v[0]);
      kt[0][kt_idx(d0 + 1, r)] = f2bf(v[1]);
      kt[0][kt_idx(d0 + 2, r)] = f2bf(v[2]);
      kt[0][kt_idx(d0 + 3, r)] = f2bf(v[3]);
    }
  }
  __syncthreads();
  int cur = 0;
  for (int g = 0; g < 128; ++g) {
    const bool more = (g < 127);
    fvec4 nf[4];
    if (more) load_chunk(K + (size_t)(g + 1) * 32 * D_, tid, nf);
    v8bf fr[8];
#pragma unroll
    for (int x = 0; x < 8; ++x) fr[x] = kt_frag(kt[cur], x * 16 + lr, lg);
#pragma unroll
    for (int mi = 0; mi < 2; ++mi)
#pragma unroll
      for (int n = 0; n < 8; ++n)
        acc[mi][n] = __builtin_amdgcn_mfma_f32_16x16x32_bf16(
            fr[2 * w + mi], fr[n], acc[mi][n], 0, 0, 0);
    if (more) {
      const int d0 = (tid & 31) * 4;
      const int rb = tid >> 5;
      u16* kb = kt[cur ^ 1];
#pragma unroll
      for (int i = 0; i < 4; ++i) {
        const int r = i * 8 + rb;
        fvec4 v = nf[i];
        kb[kt_idx(d0 + 0, r)] = f2bf(v[0]);
        kb[kt_idx(d0 + 1, r)] = f2bf(v[1]);
        kb[kt_idx(d0 + 2, r)] = f2bf(v[2]);
        kb[kt_idx(d0 + 3, r)] = f2bf(v[3]);
      }
      cur ^= 1;
    }
    __syncthreads();
  }
#pragma unroll
  for (int mi = 0; mi < 2; ++mi)
#pragma unroll
    for (int n = 0; n < 8; ++n)
#pragma unroll
      for (int j = 0; j < 4; ++j) {
        const int idx = (16 * (2 * w + mi) + 4 * lg + j) * 128 + 16 * n + lr;
        out2[idx] = carry[idx] + 0.125f * acc[mi][n][j];
      }
}

extern "C" void kernel_launch(void* const* d_in, const int* in_sizes, int n_in,
                              void* d_out, int out_size, void* d_ws,
                              size_t ws_size, hipStream_t stream) {
  const float* Q = (const float*)d_in[0];
  const float* K = (const float*)d_in[1];
  const float* carry = (const float*)d_in[2];
  float* out = (float*)d_out;
  float* out2 = out + (size_t)B_ * C_ * D_;

  // ws: G bf16 [128 chunks][16384]  (4 MiB)
  const size_t need = (size_t)128 * 16384 * sizeof(u16);

  if (ws_size >= need) {
    u16* G = (u16*)d_ws;
    k_gram<<<dim3(16, 8), 256, 0, stream>>>(K, G);
    k_out2<<<dim3(17, 8), 256, 0, stream>>>(Q, K, G, carry, out, out2);
  } else {
    k_proj_fb<<<dim3(16, 8), 256, 0, stream>>>(Q, K, carry, out);
    k_syrk_direct<<<1, 256, 0, stream>>>(K, carry, out2);
  }
}

// Round 13
// 25.927 us; speedup vs baseline: 6.4913x; 1.1660x over previous
//
#include <hip/hip_runtime.h>

#define B_ 8
#define C_ 512
#define D_ 128
#define LDG 132   // k_gram LDS row stride (u16): b64-aligned, 2-way-free gather
#define LDO 136   // k_out LDS row stride (u16): b128-aligned rows
#define LDK 136   // fallback ks row stride
#define LDT 40    // fallback kt row stride

typedef __bf16 v8bf __attribute__((ext_vector_type(8)));
typedef float v4f __attribute__((ext_vector_type(4)));
typedef float fvec4 __attribute__((ext_vector_type(4)));
typedef unsigned short u16;
typedef u16 u16x4 __attribute__((ext_vector_type(4)));
typedef u16 u16x8 __attribute__((ext_vector_type(8)));

// f32 -> bf16 round-to-nearest-even
__device__ __forceinline__ u16 f2bf(float f) {
  unsigned u = __builtin_bit_cast(unsigned, f);
  u = u + 0x7FFFu + ((u >> 16) & 1u);
  return (u16)(u >> 16);
}
__device__ __forceinline__ float bf2f(u16 h) {
  unsigned u = ((unsigned)h) << 16;
  return __builtin_bit_cast(float, u);
}

// Coalesced 32x128 f32 chunk load: 4 fvec4/thread, 4B lane stride.
__device__ __forceinline__ void load_chunk(const float* __restrict__ Kbase,
                                           int tid, fvec4* pf) {
#pragma unroll
  for (int i = 0; i < 4; ++i)
    pf[i] = *(const fvec4*)(Kbase + i * 1024 + tid * 4);
}

// Write staged chunk to LDS row-major [32][stride] bf16 (b64 stores).
template <int STRIDE>
__device__ __forceinline__ void lds_put(const fvec4* pf, u16* ksb, int tid) {
  const int d0 = (tid & 31) * 4;
  const int rb = tid >> 5;
#pragma unroll
  for (int i = 0; i < 4; ++i) {
    const int r = i * 8 + rb;
    fvec4 v = pf[i];
    u16x4 u = {f2bf(v[0]), f2bf(v[1]), f2bf(v[2]), f2bf(v[3])};
    *(u16x4*)&ksb[r * STRIDE + d0] = u;
  }
}

// ========== K1: per-chunk Gram G[b][t] = K_t^T K_t, bf16 row-major =========
// grid (16,8), 256 thr. Coalesced global -> LDS -> conflict-light gather.
__global__ __launch_bounds__(256, 1) void k_gram(const float* __restrict__ K,
                                                 u16* __restrict__ G) {
  const int t = blockIdx.x, b = blockIdx.y;
  const int tid = threadIdx.x;
  const int w = tid >> 6, l = tid & 63, lr = l & 15, lg = l >> 4;

  __shared__ u16 ks[32 * LDG];

  fvec4 pf[4];
  load_chunk(K + (size_t)(b * C_ + t * 32) * D_, tid, pf);
  lds_put<LDG>(pf, ks, tid);
  __syncthreads();

  // fr[n][e] = bf16(K[8lg+e][16n+lr]) from LDS
  v8bf fr[8];
#pragma unroll
  for (int n = 0; n < 8; ++n) {
    u16 tmp[8];
#pragma unroll
    for (int e = 0; e < 8; ++e) tmp[e] = ks[(8 * lg + e) * LDG + 16 * n + lr];
    fr[n] = *(const v8bf*)tmp;
  }
  u16* Gp = G + (size_t)(b * 16 + t) * 16384;
#pragma unroll
  for (int mi = 0; mi < 2; ++mi) {
    v8bf am = fr[2 * w + mi];
#pragma unroll
    for (int n = 0; n < 8; ++n) {
      v4f z = {0.f, 0.f, 0.f, 0.f};
      v4f a = __builtin_amdgcn_mfma_f32_16x16x32_bf16(am, fr[n], z, 0, 0, 0);
#pragma unroll
      for (int j = 0; j < 4; ++j)
        Gp[(size_t)(32 * w + 16 * mi + 4 * lg + j) * 128 + 16 * n + lr] =
            f2bf(a[j]);
    }
  }
}

// ====== K2: exclusive prefix -> M' (bf16, carry folded) + totals (f32) =====
// grid (16,8) = 128 blocks, 1024-elem slices, 4 elems/thread.
__global__ __launch_bounds__(256, 1) void k_prefix(
    const u16* __restrict__ G, const float* __restrict__ carry,
    u16* __restrict__ Mp, float* __restrict__ tot) {
  const int b = blockIdx.y;
  const int e0 = blockIdx.x * 1024 + threadIdx.x * 4;
  fvec4 c4 = *(const fvec4*)(carry + e0);
  float run0 = 0.f, run1 = 0.f, run2 = 0.f, run3 = 0.f;
  const u16* gb = G + (size_t)b * 16 * 16384 + e0;
  u16* mb = Mp + (size_t)b * 16 * 16384 + e0;
#pragma unroll
  for (int t = 0; t < 16; ++t) {
    u16x4 g = *(const u16x4*)(gb + (size_t)t * 16384);
    u16x4 m = {f2bf(c4[0] + run0), f2bf(c4[1] + run1), f2bf(c4[2] + run2),
               f2bf(c4[3] + run3)};
    *(u16x4*)(mb + (size_t)t * 16384) = m;
    run0 += bf2f(g[0]);
    run1 += bf2f(g[1]);
    run2 += bf2f(g[2]);
    run3 += bf2f(g[3]);
  }
  fvec4 rr = {run0, run1, run2, run3};
  *(fvec4*)(tot + (size_t)b * 16384 + e0) = rr;
}

// ===== K3: out = Q*M'^T + intra-chunk causal S*K ; t==16 blocks do out2 ====
// grid (17,8), 256 thr / 4 waves. (256,1): keep all 16 M' frags resident.
__global__ __launch_bounds__(256, 1) void k_out(
    const float* __restrict__ Q, const float* __restrict__ K,
    const u16* __restrict__ Mp, const float* __restrict__ tot,
    const float* __restrict__ carry, float* __restrict__ out,
    float* __restrict__ out2) {
  const int t = blockIdx.x, b = blockIdx.y;
  const int tid = threadIdx.x;

  if (t == 16) {  // out2 = carry + mean_b(tot)
    const int e0 = b * 2048 + tid * 8;
    fvec4 s0 = {0.f, 0.f, 0.f, 0.f}, s1 = {0.f, 0.f, 0.f, 0.f};
#pragma unroll
    for (int bb = 0; bb < 8; ++bb) {
      s0 += *(const fvec4*)(tot + (size_t)bb * 16384 + e0);
      s1 += *(const fvec4*)(tot + (size_t)bb * 16384 + e0 + 4);
    }
    fvec4 c0 = *(const fvec4*)(carry + e0);
    fvec4 c1 = *(const fvec4*)(carry + e0 + 4);
    *(fvec4*)(out2 + e0) = c0 + 0.125f * s0;
    *(fvec4*)(out2 + e0 + 4) = c1 + 0.125f * s1;
    return;
  }

  const int w = tid >> 6, l = tid & 63, lr = l & 15, lg = l >> 4;
  const int wr = (w & 1) * 16, wc = (w >> 1) * 64, sc0 = (w >> 1) * 16;
  const int r0 = t * 32;

  __shared__ u16 ks[32 * LDO];
  __shared__ u16 sl[32 * 40];

  // stage K chunk (coalesced) into LDS
  fvec4 pf[4];
  load_chunk(K + (size_t)(b * C_ + r0) * D_, tid, pf);

  // Q A-frags from global (contiguous rows)
  v8bf qf[4];
  {
    const float* qrow = Q + (size_t)(b * C_ + r0 + wr + lr) * D_;
#pragma unroll
    for (int kk = 0; kk < 4; ++kk) {
      const float* p = qrow + kk * 32 + 8 * lg;
      fvec4 a = *(const fvec4*)p;
      fvec4 c2 = *(const fvec4*)(p + 4);
      u16 tmp[8] = {f2bf(a[0]),  f2bf(a[1]),  f2bf(a[2]),  f2bf(a[3]),
                    f2bf(c2[0]), f2bf(c2[1]), f2bf(c2[2]), f2bf(c2[3])};
      qf[kk] = *(const v8bf*)tmp;
    }
  }

  // M' B-frags: direct bf16 b128 global loads (16 in flight)
  v8bf mf[16];
  {
    const u16* mp = Mp + (size_t)(b * 16 + t) * 16384;
#pragma unroll
    for (int kk = 0; kk < 4; ++kk)
#pragma unroll
      for (int n = 0; n < 4; ++n)
        mf[kk * 4 + n] = *(const v8bf*)(mp + (size_t)(wc + 16 * n + lr) * 128 +
                                        32 * kk + 8 * lg);
  }

  lds_put<LDO>(pf, ks, tid);
  __syncthreads();

  // S-step B-frags: row-major b128 LDS reads
  v8bf sb[4];
#pragma unroll
  for (int kk = 0; kk < 4; ++kk)
    sb[kk] = *(const v8bf*)&ks[(sc0 + lr) * LDO + 32 * kk + 8 * lg];

  // PV B-frags: transposed LDS gather
  v8bf pb[4];
#pragma unroll
  for (int n = 0; n < 4; ++n) {
    u16 tmp[8];
#pragma unroll
    for (int e = 0; e < 8; ++e)
      tmp[e] = ks[(8 * lg + e) * LDO + wc + 16 * n + lr];
    pb[n] = *(const v8bf*)tmp;
  }

  // S tile = Q * Kchunk^T (diagonal, causal mask), hand off via LDS
  v4f sacc = {0.f, 0.f, 0.f, 0.f};
#pragma unroll
  for (int kk = 0; kk < 4; ++kk)
    sacc =
        __builtin_amdgcn_mfma_f32_16x16x32_bf16(qf[kk], sb[kk], sacc, 0, 0, 0);
#pragma unroll
  for (int j = 0; j < 4; ++j) {
    const int sr = wr + lg * 4 + j;
    const int sc = sc0 + lr;
    float v = sacc[j];
    if (sc > sr) v = 0.f;
    sl[sr * 40 + sc] = f2bf(v);
  }

  // acc = Q * M'^T (M' already includes carry) — overlaps the barrier wait
  v4f acc[4] = {{0.f, 0.f, 0.f, 0.f}, {0.f, 0.f, 0.f, 0.f},
                {0.f, 0.f, 0.f, 0.f}, {0.f, 0.f, 0.f, 0.f}};
#pragma unroll
  for (int kk = 0; kk < 4; ++kk)
#pragma unroll
    for (int n = 0; n < 4; ++n)
      acc[n] = __builtin_amdgcn_mfma_f32_16x16x32_bf16(qf[kk], mf[kk * 4 + n],
                                                       acc[n], 0, 0, 0);
  __syncthreads();

  // PV: acc += S * Kchunk
  v8bf af = *(const v8bf*)&sl[(wr + lr) * 40 + lg * 8];
#pragma unroll
  for (int n = 0; n < 4; ++n)
    acc[n] =
        __builtin_amdgcn_mfma_f32_16x16x32_bf16(af, pb[n], acc[n], 0, 0, 0);

  // epilogue: C/D layout col = lane&15, row = 4*(lane>>4)+j
#pragma unroll
  for (int n = 0; n < 4; ++n)
#pragma unroll
    for (int j = 0; j < 4; ++j)
      out[(size_t)(b * C_ + r0 + wr + lg * 4 + j) * D_ + wc + n * 16 + lr] =
          acc[n][j];
}

// ================= fallback path (ws too small) ============================
__device__ __forceinline__ int kt_idx(int d, int r) {
  return d * LDT + ((((r >> 3) ^ ((d >> 2) & 3))) << 3) + (r & 7);
}
__device__ __forceinline__ v8bf kt_frag(const u16* ktb, int col, int lg) {
  return *(const v8bf*)&ktb[col * LDT + (((lg ^ ((col >> 2) & 3))) << 3)];
}
__device__ __forceinline__ void write_stage(const fvec4* pf, u16* ksb, u16* ktb,
                                            int tid) {
  const int d0 = (tid & 31) * 4;
  const int rb = tid >> 5;
#pragma unroll
  for (int i = 0; i < 4; ++i) {
    const int r = i * 8 + rb;
    fvec4 v = pf[i];
    u16 h0 = f2bf(v[0]), h1 = f2bf(v[1]), h2 = f2bf(v[2]), h3 = f2bf(v[3]);
    u16x4 u = {h0, h1, h2, h3};
    *(u16x4*)&ksb[r * LDK + d0] = u;
    ktb[kt_idx(d0 + 0, r)] = h0;
    ktb[kt_idx(d0 + 1, r)] = h1;
    ktb[kt_idx(d0 + 2, r)] = h2;
    ktb[kt_idx(d0 + 3, r)] = h3;
  }
}

__global__ __launch_bounds__(256) void k_proj_fb(
    const float* __restrict__ Q, const float* __restrict__ K,
    const float* __restrict__ carry, float* __restrict__ out) {
  const int t = blockIdx.x, b = blockIdx.y;
  const int tid = threadIdx.x;
  const int w = tid >> 6, l = tid & 63, lr = l & 15, lg = l >> 4;
  const int wr = (w & 1) * 16, wc = (w >> 1) * 64;
  const int r0 = t * 32;

  __shared__ u16 ks[2][32 * LDK];
  __shared__ u16 kt[2][128 * LDT];
  __shared__ u16 sl[32 * 40];

  const float* Kb0 = K + (size_t)(b * C_) * D_;
  fvec4 pf[4];
  load_chunk(Kb0, tid, pf);

  v8bf qf[4];
  {
    const float* qrow = Q + (size_t)(b * C_ + r0 + wr + lr) * D_;
#pragma unroll
    for (int kk = 0; kk < 4; ++kk) {
      const float* p = qrow + kk * 32 + lg * 8;
      fvec4 a = *(const fvec4*)p;
      fvec4 c2 = *(const fvec4*)(p + 4);
      u16 tmp[8] = {f2bf(a[0]),  f2bf(a[1]),  f2bf(a[2]),  f2bf(a[3]),
                    f2bf(c2[0]), f2bf(c2[1]), f2bf(c2[2]), f2bf(c2[3])};
      qf[kk] = *(const v8bf*)tmp;
    }
  }

  v4f acc[4] = {{0.f, 0.f, 0.f, 0.f}, {0.f, 0.f, 0.f, 0.f},
                {0.f, 0.f, 0.f, 0.f}, {0.f, 0.f, 0.f, 0.f}};
#pragma unroll
  for (int kk = 0; kk < 4; ++kk) {
#pragma unroll
    for (int n = 0; n < 4; ++n) {
      const float* p =
          carry + (size_t)(wc + n * 16 + lr) * D_ + kk * 32 + lg * 8;
      fvec4 a = *(const fvec4*)p;
      fvec4 c2 = *(const fvec4*)(p + 4);
      u16 tmp[8] = {f2bf(a[0]),  f2bf(a[1]),  f2bf(a[2]),  f2bf(a[3]),
                    f2bf(c2[0]), f2bf(c2[1]), f2bf(c2[2]), f2bf(c2[3])};
      acc[n] = __builtin_amdgcn_mfma_f32_16x16x32_bf16(
          qf[kk], *(const v8bf*)tmp, acc[n], 0, 0, 0);
    }
  }

  write_stage(pf, ks[0], kt[0], tid);
  __syncthreads();

  int cur = 0;
  const int sc0 = (w >> 1) * 16;
  for (int cc = 0; cc <= t; ++cc) {
    const bool more = (cc < t);
    fvec4 nf[4];
    if (more) load_chunk(Kb0 + (size_t)(cc + 1) * 32 * D_, tid, nf);

    v4f sacc = {0.f, 0.f, 0.f, 0.f};
#pragma unroll
    for (int kk = 0; kk < 4; ++kk) {
      v8bf bf = *(const v8bf*)&ks[cur][(sc0 + lr) * LDK + kk * 32 + lg * 8];
      sacc = __builtin_amdgcn_mfma_f32_16x16x32_bf16(qf[kk], bf, sacc, 0, 0, 0);
    }
    const bool diag = (cc == t);
#pragma unroll
    for (int j = 0; j < 4; ++j) {
      const int sr = wr + lg * 4 + j;
      const int sc = sc0 + lr;
      float v = sacc[j];
      if (diag && sc > sr) v = 0.f;
      sl[sr * 40 + sc] = f2bf(v);
    }
    __syncthreads();

    v8bf af = *(const v8bf*)&sl[(wr + lr) * 40 + lg * 8];
#pragma unroll
    for (int n = 0; n < 4; ++n) {
      v8bf bf = kt_frag(kt[cur], wc + n * 16 + lr, lg);
      acc[n] = __builtin_amdgcn_mfma_f32_16x16x32_bf16(af, bf, acc[n], 0, 0, 0);
    }
    if (more) {
      write_stage(nf, ks[cur ^ 1], kt[cur ^ 1], tid);
      cur ^= 1;
    }
    __syncthreads();
  }

#pragma unroll
  for (int n = 0; n < 4; ++n)
#pragma unroll
    for (int j = 0; j < 4; ++j)
      out[(size_t)(b * C_ + r0 + wr + lg * 4 + j) * D_ + wc + n * 16 + lr] =
          acc[n][j];
}

__global__ __launch_bounds__(256) void k_syrk_direct(
    const float* __restrict__ K, const float* __restrict__ carry,
    float* __restrict__ out2) {
  const int tid = threadIdx.x;
  const int w = tid >> 6, l = tid & 63, lr = l & 15, lg = l >> 4;
  __shared__ u16 kt[2][128 * LDT];

  v4f acc[2][8];
#pragma unroll
  for (int mi = 0; mi < 2; ++mi)
#pragma unroll
    for (int n = 0; n < 8; ++n) acc[mi][n] = (v4f){0.f, 0.f, 0.f, 0.f};

  fvec4 pf[4];
  load_chunk(K, tid, pf);
  {
    const int d0 = (tid & 31) * 4;
    const int rb = tid >> 5;
#pragma unroll
    for (int i = 0; i < 4; ++i) {
      const int r = i * 8 + rb;
      fvec4 v = pf[i];
      kt[0][kt_idx(d0 + 0, r)] = f2bf(v[0]);
      kt[0][kt_idx(d0 + 1, r)] = f2bf(v[1]);
      kt[0][kt_idx(d0 + 2, r)] = f2bf(v[2]);
      kt[0][kt_idx(d0 + 3, r)] = f2bf(v[3]);
    }
  }
  __syncthreads();
  int cur = 0;
  for (int g = 0; g < 128; ++g) {
    const bool more = (g < 127);
    fvec4 nf[4];
    if (more) load_chunk(K + (size_t)(g + 1) * 32 * D_, tid, nf);
    v8bf fr[8];
#pragma unroll
    for (int x = 0; x < 8; ++x) fr[x] = kt_frag(kt[cur], x * 16 + lr, lg);
#pragma unroll
    for (int mi = 0; mi < 2; ++mi)
#pragma unroll
      for (int n = 0; n < 8; ++n)
        acc[mi][n] = __builtin_amdgcn_mfma_f32_16x16x32_bf16(
            fr[2 * w + mi], fr[n], acc[mi][n], 0, 0, 0);
    if (more) {
      const int d0 = (tid & 31) * 4;
      const int rb = tid >> 5;
      u16* kb = kt[cur ^ 1];
#pragma unroll
      for (int i = 0; i < 4; ++i) {
        const int r = i * 8 + rb;
        fvec4 v = nf[i];
        kb[kt_idx(d0 + 0, r)] = f2bf(v[0]);
        kb[kt_idx(d0 + 1, r)] = f2bf(v[1]);
        kb[kt_idx(d0 + 2, r)] = f2bf(v[2]);
        kb[kt_idx(d0 + 3, r)] = f2bf(v[3]);
      }
      cur ^= 1;
    }
    __syncthreads();
  }
#pragma unroll
  for (int mi = 0; mi < 2; ++mi)
#pragma unroll
    for (int n = 0; n < 8; ++n)
#pragma unroll
      for (int j = 0; j < 4; ++j) {
        const int idx = (16 * (2 * w + mi) + 4 * lg + j) * 128 + 16 * n + lr;
        out2[idx] = carry[idx] + 0.125f * acc[mi][n][j];
      }
}

extern "C" void kernel_launch(void* const* d_in, const int* in_sizes, int n_in,
                              void* d_out, int out_size, void* d_ws,
                              size_t ws_size, hipStream_t stream) {
  const float* Q = (const float*)d_in[0];
  const float* K = (const float*)d_in[1];
  const float* carry = (const float*)d_in[2];
  float* out = (float*)d_out;
  float* out2 = out + (size_t)B_ * C_ * D_;

  // ws: G bf16 [128][16384] | M' bf16 [128][16384] | tot f32 [8][16384]
  const size_t nGu = (size_t)128 * 16384;  // u16 elements each for G and M'
  const size_t need = nGu * 2 * sizeof(u16) + (size_t)8 * 16384 * sizeof(float);

  if (ws_size >= need) {
    u16* G = (u16*)d_ws;
    u16* Mp = G + nGu;
    float* tot = (float*)(Mp + nGu);
    k_gram<<<dim3(16, 8), 256, 0, stream>>>(K, G);
    k_prefix<<<dim3(16, 8), 256, 0, stream>>>(G, carry, Mp, tot);
    k_out<<<dim3(17, 8), 256, 0, stream>>>(Q, K, Mp, tot, carry, out, out2);
  } else {
    k_proj_fb<<<dim3(16, 8), 256, 0, stream>>>(Q, K, carry, out);
    k_syrk_direct<<<1, 256, 0, stream>>>(K, carry, out2);
  }
}